// Round 1
// baseline (140.184 us; speedup 1.0000x reference)
//
#include <hip/hip_runtime.h>
#include <stdint.h>

#define NEGC 1000000000000.0f

using f32x4  = __attribute__((ext_vector_type(4))) float;
using short8 = __attribute__((ext_vector_type(8))) short;

typedef __attribute__((address_space(3))) uint32_t* lds_ptr_t;
typedef const __attribute__((address_space(1))) uint32_t* gptr_t;

__device__ __forceinline__ void gload_lds16(const void* g, const void* l) {
  // async global->LDS, 16B per lane; LDS dest = wave-uniform base + lane*16
  __builtin_amdgcn_global_load_lds((gptr_t)g, (lds_ptr_t)l, 16, 0, 0);
}

__device__ __forceinline__ unsigned short f2bf(float f) {
  union { float f; uint32_t u; } v; v.f = f;
  uint32_t u = v.u;
  return (unsigned short)((u + 0x7fffu + ((u >> 16) & 1u)) >> 16);
}

// ---------------- kernel 1: RoPE sin/cos table [1024][32] ----------------
__global__ void k_sincos(float* __restrict__ s, float* __restrict__ c) {
  int idx = blockIdx.x * 256 + threadIdx.x;   // 32768
  int m = idx >> 5, i = idx & 31;
  float inv = expf(-(float)i * (9.210340371976184f / 32.0f)); // 10000^(-i/32)
  float ang = (float)m * inv;
  s[idx] = sinf(ang);
  c[idx] = cosf(ang);
}

// ---------------- kernel 2: fp32 -> bf16 cast (inputs) ----------------
__global__ void k_cvt(const float* __restrict__ in, unsigned short* __restrict__ out, int n4) {
  int idx = blockIdx.x * blockDim.x + threadIdx.x;
  if (idx < n4) {
    float4 v = ((const float4*)in)[idx];
    ushort4 o;
    o.x = f2bf(v.x); o.y = f2bf(v.y); o.z = f2bf(v.z); o.w = f2bf(v.w);
    ((ushort4*)out)[idx] = o;
  }
}

// ---------------- kernel 3: W[768][1536] -> Wt[1536][768] bf16 ----------------
__global__ void k_transW(const float* __restrict__ W, unsigned short* __restrict__ Wt) {
  __shared__ float tile[64][65];
  int kb = blockIdx.x;   // 12 blocks of K
  int nb = blockIdx.y;   // 24 blocks of N
  int t = threadIdx.x;
  int c = t & 63, r0 = t >> 6;
#pragma unroll
  for (int p = 0; p < 16; ++p) {
    int r = r0 + p * 4;
    tile[r][c] = W[(size_t)(kb * 64 + r) * 1536 + nb * 64 + c];
  }
  __syncthreads();
#pragma unroll
  for (int p = 0; p < 16; ++p) {
    int n = r0 + p * 4;
    Wt[(size_t)(nb * 64 + n) * 768 + kb * 64 + c] = f2bf(tile[c][n]);
  }
}

// ---------------- kernel 4: x = A@W^T + b, fused RoPE, split q/k ----------------
// A: [8192][768] bf16, Bt: [1536][768] bf16.  Output q,k: [8][12][1024][64] bf16.
__global__ __launch_bounds__(256) void k_gemm1(
    const unsigned short* __restrict__ A,
    const unsigned short* __restrict__ Bt,
    const float* __restrict__ bias,
    const float* __restrict__ ssin, const float* __restrict__ scos,
    unsigned short* __restrict__ qb, unsigned short* __restrict__ kb) {
  __shared__ __align__(16) unsigned short As[128 * 64];
  __shared__ __align__(16) unsigned short Bs[128 * 64];
  const int tid = threadIdx.x;
  const int wave = tid >> 6, lane = tid & 63;
  const int wm = wave >> 1, wn = wave & 1;
  const int m0 = blockIdx.x * 128;
  const int h  = blockIdx.y;        // head (1536/128 == 12 heads, one per col-block)
  const int j0 = h * 128;
  const int lr = lane >> 3, kc = lane & 7;

  f32x4 acc[4][4] = {};

  for (int kt = 0; kt < 12; ++kt) {
    const int k0 = kt * 64;
#pragma unroll
    for (int i = 0; i < 4; ++i) {
      int row = i * 32 + wave * 8 + lr;
      int gk = k0 + ((kc ^ (row & 7)) << 3);          // pre-swizzled source (rule #21)
      gload_lds16(&A[(size_t)(m0 + row) * 768 + gk], &As[(i * 32 + wave * 8) * 64]);
    }
#pragma unroll
    for (int i = 0; i < 4; ++i) {
      int row = i * 32 + wave * 8 + lr;
      int gk = k0 + ((kc ^ (row & 7)) << 3);
      gload_lds16(&Bt[(size_t)(j0 + row) * 768 + gk], &Bs[(i * 32 + wave * 8) * 64]);
    }
    asm volatile("s_waitcnt vmcnt(0)" ::: "memory");
    __syncthreads();
#pragma unroll
    for (int kh = 0; kh < 2; ++kh) {
      short8 af[4], bfr[4];
#pragma unroll
      for (int mt = 0; mt < 4; ++mt) {
        int row = wm * 64 + mt * 16 + (lane & 15);
        int cs = (kh * 4 + (lane >> 4)) ^ (row & 7);  // swizzled read
        af[mt] = *(const short8*)&As[row * 64 + cs * 8];
      }
#pragma unroll
      for (int nt = 0; nt < 4; ++nt) {
        int row = wn * 64 + nt * 16 + (lane & 15);
        int cs = (kh * 4 + (lane >> 4)) ^ (row & 7);
        bfr[nt] = *(const short8*)&Bs[row * 64 + cs * 8];
      }
#pragma unroll
      for (int mt = 0; mt < 4; ++mt)
#pragma unroll
        for (int nt = 0; nt < 4; ++nt)
          acc[mt][nt] = __builtin_amdgcn_mfma_f32_16x16x32_bf16(af[mt], bfr[nt], acc[mt][nt], 0, 0, 0);
    }
    __syncthreads();
  }

  // epilogue: bias + RoPE + write bf16. C layout: col=lane&15, row=(lane>>4)*4+j.
  // adjacent head-dims sit in adjacent lanes -> pair exchange via shfl_xor(1).
  const int col = lane & 15, rquad = lane >> 4;
  unsigned short* dst = (wn == 0) ? qb : kb;
#pragma unroll
  for (int nt = 0; nt < 4; ++nt) {
    const int d = nt * 16 + col;                  // head dim 0..63
    const float bv = bias[j0 + wn * 64 + d];
    const int ifr = d >> 1;
    const float sgn = (d & 1) ? 1.0f : -1.0f;
#pragma unroll
    for (int mt = 0; mt < 4; ++mt) {
#pragma unroll
      for (int j = 0; j < 4; ++j) {
        int mg = m0 + wm * 64 + mt * 16 + rquad * 4 + j;
        int ms = mg & 1023, bi = mg >> 10;
        float v = acc[mt][nt][j] + bv;
        float p = __shfl_xor(v, 1, 64);           // partner dim (d^1), incl. its bias
        float s = ssin[ms * 32 + ifr], cv = scos[ms * 32 + ifr];
        float r = v * cv + sgn * p * s;           // even: v*c - p*s ; odd: v*c + p*s
        dst[(size_t)((bi * 12 + h) * 1024 + ms) * 64 + d] = f2bf(r);
      }
    }
  }
}

// ---------------- kernel 5: logits[b][h][m][n] = q.k, mask+tril+scale ----------------
__global__ __launch_bounds__(256) void k_gemm2(
    const unsigned short* __restrict__ qb, const unsigned short* __restrict__ kbuf,
    const float* __restrict__ mask, float* __restrict__ out) {
  __shared__ __align__(16) unsigned short Qs[128 * 64];
  __shared__ __align__(16) unsigned short Ks[128 * 64];
  const int tid = threadIdx.x;
  const int wave = tid >> 6, lane = tid & 63;
  const int wm = wave >> 1, wn = wave & 1;
  const int bh = blockIdx.y;              // 0..95 = b*12+h
  const int tm = blockIdx.x >> 3, tn = blockIdx.x & 7;
  const int b = bh / 12;
  const int lr = lane >> 3, kc = lane & 7;

  const unsigned short* qbase = qb   + (size_t)bh * (1024 * 64);
  const unsigned short* kbase = kbuf + (size_t)bh * (1024 * 64);

#pragma unroll
  for (int i = 0; i < 4; ++i) {
    int row = i * 32 + wave * 8 + lr;
    int gk = (kc ^ (row & 7)) << 3;
    gload_lds16(&qbase[(size_t)(tm * 128 + row) * 64 + gk], &Qs[(i * 32 + wave * 8) * 64]);
  }
#pragma unroll
  for (int i = 0; i < 4; ++i) {
    int row = i * 32 + wave * 8 + lr;
    int gk = (kc ^ (row & 7)) << 3;
    gload_lds16(&kbase[(size_t)(tn * 128 + row) * 64 + gk], &Ks[(i * 32 + wave * 8) * 64]);
  }
  asm volatile("s_waitcnt vmcnt(0)" ::: "memory");
  __syncthreads();

  f32x4 acc[4][4] = {};
#pragma unroll
  for (int kh = 0; kh < 2; ++kh) {
    short8 af[4], bfr[4];
#pragma unroll
    for (int mt = 0; mt < 4; ++mt) {
      int row = wm * 64 + mt * 16 + (lane & 15);
      int cs = (kh * 4 + (lane >> 4)) ^ (row & 7);
      af[mt] = *(const short8*)&Qs[row * 64 + cs * 8];
    }
#pragma unroll
    for (int nt = 0; nt < 4; ++nt) {
      int row = wn * 64 + nt * 16 + (lane & 15);
      int cs = (kh * 4 + (lane >> 4)) ^ (row & 7);
      bfr[nt] = *(const short8*)&Ks[row * 64 + cs * 8];
    }
#pragma unroll
    for (int mt = 0; mt < 4; ++mt)
#pragma unroll
      for (int nt = 0; nt < 4; ++nt)
        acc[mt][nt] = __builtin_amdgcn_mfma_f32_16x16x32_bf16(af[mt], bfr[nt], acc[mt][nt], 0, 0, 0);
  }

  float* obase = out + (size_t)bh * (1024 * 1024);
  const int col = lane & 15, rquad = lane >> 4;
  float m2v[4]; int ngv[4];
#pragma unroll
  for (int nt = 0; nt < 4; ++nt) {
    ngv[nt] = tn * 128 + wn * 64 + nt * 16 + col;
    m2v[nt] = mask[b * 1024 + ngv[nt]];
  }
#pragma unroll
  for (int mt = 0; mt < 4; ++mt) {
#pragma unroll
    for (int j = 0; j < 4; ++j) {
      int mg = tm * 128 + wm * 64 + mt * 16 + rquad * 4 + j;
      float m1 = mask[b * 1024 + mg];
      float* orow = obase + (size_t)mg * 1024;
#pragma unroll
      for (int nt = 0; nt < 4; ++nt) {
        float v = acc[mt][nt][j];
        v = v * m1 - NEGC * (1.0f - m1);
        v = v * m2v[nt] - NEGC * (1.0f - m2v[nt]);
        if (ngv[nt] < mg) v -= NEGC;           // tril(k=-1): n < m
        orow[ngv[nt]] = v * 0.125f;            // / sqrt(64)
      }
    }
  }
}

extern "C" void kernel_launch(void* const* d_in, const int* in_sizes, int n_in,
                              void* d_out, int out_size, void* d_ws, size_t ws_size,
                              hipStream_t stream) {
  const float* inputs = (const float*)d_in[0];  // [8][1024][768]
  const float* mask   = (const float*)d_in[1];  // [8][1024]
  const float* W      = (const float*)d_in[2];  // [768][1536]
  const float* bias   = (const float*)d_in[3];  // [1536]
  float* out = (float*)d_out;                   // [8][12][1024][1024]
  char* ws = (char*)d_ws;

  float* ssin = (float*)(ws);                                   // 128 KB
  float* scos = (float*)(ws + 131072);                          // 128 KB
  unsigned short* inA = (unsigned short*)(ws + 262144);         // 12.6 MB
  unsigned short* Wt  = (unsigned short*)(ws + 262144 + 12582912);            // 2.36 MB
  unsigned short* qb  = (unsigned short*)(ws + 262144 + 12582912 + 2359296);  // 12.6 MB
  unsigned short* kb  = (unsigned short*)(ws + 262144 + 12582912 + 2359296 + 12582912);

  hipLaunchKernelGGL(k_sincos, dim3(128), dim3(256), 0, stream, ssin, scos);
  hipLaunchKernelGGL(k_cvt, dim3(6144), dim3(256), 0, stream, inputs, inA, 1572864);
  hipLaunchKernelGGL(k_transW, dim3(12, 24), dim3(256), 0, stream, W, Wt);
  hipLaunchKernelGGL(k_gemm1, dim3(64, 12), dim3(256), 0, stream,
                     inA, Wt, bias, ssin, scos, qb, kb);
  hipLaunchKernelGGL(k_gemm2, dim3(64, 96), dim3(256), 0, stream, qb, kb, mask, out);
}

// Round 2
// 130.794 us; speedup vs baseline: 1.0718x; 1.0718x over previous
//
#include <hip/hip_runtime.h>
#include <stdint.h>

#define NEGC 1000000000000.0f

using f32x4  = __attribute__((ext_vector_type(4))) float;
using short8 = __attribute__((ext_vector_type(8))) short;

typedef __attribute__((address_space(3))) uint32_t* lds_ptr_t;
typedef const __attribute__((address_space(1))) uint32_t* gptr_t;

__device__ __forceinline__ void gload_lds16(const void* g, const void* l) {
  // async global->LDS, 16B per lane; LDS dest = wave-uniform base + lane*16
  __builtin_amdgcn_global_load_lds((gptr_t)g, (lds_ptr_t)l, 16, 0, 0);
}

__device__ __forceinline__ unsigned short f2bf(float f) {
  union { float f; uint32_t u; } v; v.f = f;
  uint32_t u = v.u;
  return (unsigned short)((u + 0x7fffu + ((u >> 16) & 1u)) >> 16);
}

// ---------------- fused prep: cvt (blocks 0..6143) | transW (6144..6431) | sincos (6432..6559) ----
__global__ __launch_bounds__(256) void k_prep(
    const float* __restrict__ in, unsigned short* __restrict__ inb,
    const float* __restrict__ W, unsigned short* __restrict__ Wt,
    float* __restrict__ ssin, float* __restrict__ scos) {
  __shared__ float tile[64][65];
  const int bx = blockIdx.x, t = threadIdx.x;
  if (bx < 6144) {
    // fp32 -> bf16 cast of inputs, float4-vectorized (1572864 float4's exactly)
    int idx = bx * 256 + t;
    float4 v = ((const float4*)in)[idx];
    ushort4 o;
    o.x = f2bf(v.x); o.y = f2bf(v.y); o.z = f2bf(v.z); o.w = f2bf(v.w);
    ((ushort4*)inb)[idx] = o;
  } else if (bx < 6432) {
    // W[768][1536] -> Wt[1536][768] bf16, 64x64 LDS-tiled transpose
    int b = bx - 6144;
    int kb = b % 12, nb = b / 12;
    int c = t & 63, r0 = t >> 6;
#pragma unroll
    for (int p = 0; p < 16; ++p) {
      int r = r0 + p * 4;
      tile[r][c] = W[(size_t)(kb * 64 + r) * 1536 + nb * 64 + c];
    }
    __syncthreads();
#pragma unroll
    for (int p = 0; p < 16; ++p) {
      int n = r0 + p * 4;
      Wt[(size_t)(nb * 64 + n) * 768 + kb * 64 + c] = f2bf(tile[c][n]);
    }
  } else {
    // RoPE sin/cos table [1024][32]
    int idx = (bx - 6432) * 256 + t;     // 32768
    int m = idx >> 5, i = idx & 31;
    float inv = expf(-(float)i * (9.210340371976184f / 32.0f)); // 10000^(-i/32)
    float ang = (float)m * inv;
    ssin[idx] = sinf(ang);
    scos[idx] = cosf(ang);
  }
}

// ---------------- kernel 2: x = A@W^T + b, fused RoPE, split q/k ----------------
// A: [8192][768] bf16, Bt: [1536][768] bf16.  Output q,k: [8][12][1024][64] bf16.
// XCD-chunked: each XCD owns 8 m-supertiles x 12 heads (heads-fastest -> A-tile L2-reuse).
__global__ __launch_bounds__(256) void k_gemm1(
    const unsigned short* __restrict__ A,
    const unsigned short* __restrict__ Bt,
    const float* __restrict__ bias,
    const float* __restrict__ ssin, const float* __restrict__ scos,
    unsigned short* __restrict__ qb, unsigned short* __restrict__ kb) {
  __shared__ __align__(16) unsigned short As[128 * 64];
  __shared__ __align__(16) unsigned short Bs[128 * 64];
  const int tid = threadIdx.x;
  const int wave = tid >> 6, lane = tid & 63;
  const int wm = wave >> 1, wn = wave & 1;
  // XCD swizzle: 768 blocks, 96 per XCD = 8 m-tiles x 12 heads
  const int orig = blockIdx.x;
  const int xcd = orig & 7, idx = orig >> 3;      // idx in [0,96)
  const int mt8 = idx / 12;
  const int h   = idx - mt8 * 12;                 // head 0..11
  const int m0  = (xcd * 8 + mt8) * 128;
  const int j0  = h * 128;
  const int lr = lane >> 3, kc = lane & 7;

  f32x4 acc[4][4] = {};

  for (int kt = 0; kt < 12; ++kt) {
    const int k0 = kt * 64;
#pragma unroll
    for (int i = 0; i < 4; ++i) {
      int row = i * 32 + wave * 8 + lr;
      int gk = k0 + ((kc ^ (row & 7)) << 3);          // pre-swizzled source (rule #21)
      gload_lds16(&A[(size_t)(m0 + row) * 768 + gk], &As[(i * 32 + wave * 8) * 64]);
    }
#pragma unroll
    for (int i = 0; i < 4; ++i) {
      int row = i * 32 + wave * 8 + lr;
      int gk = k0 + ((kc ^ (row & 7)) << 3);
      gload_lds16(&Bt[(size_t)(j0 + row) * 768 + gk], &Bs[(i * 32 + wave * 8) * 64]);
    }
    asm volatile("s_waitcnt vmcnt(0)" ::: "memory");
    __syncthreads();
#pragma unroll
    for (int kh = 0; kh < 2; ++kh) {
      short8 af[4], bfr[4];
#pragma unroll
      for (int mt = 0; mt < 4; ++mt) {
        int row = wm * 64 + mt * 16 + (lane & 15);
        int cs = (kh * 4 + (lane >> 4)) ^ (row & 7);  // swizzled read
        af[mt] = *(const short8*)&As[row * 64 + cs * 8];
      }
#pragma unroll
      for (int nt = 0; nt < 4; ++nt) {
        int row = wn * 64 + nt * 16 + (lane & 15);
        int cs = (kh * 4 + (lane >> 4)) ^ (row & 7);
        bfr[nt] = *(const short8*)&Bs[row * 64 + cs * 8];
      }
#pragma unroll
      for (int mt = 0; mt < 4; ++mt)
#pragma unroll
        for (int nt = 0; nt < 4; ++nt)
          acc[mt][nt] = __builtin_amdgcn_mfma_f32_16x16x32_bf16(af[mt], bfr[nt], acc[mt][nt], 0, 0, 0);
    }
    __syncthreads();
  }

  // epilogue: bias + RoPE + write bf16. C layout: col=lane&15, row=(lane>>4)*4+j.
  // adjacent head-dims sit in adjacent lanes -> pair exchange via shfl_xor(1).
  const int col = lane & 15, rquad = lane >> 4;
  unsigned short* dst = (wn == 0) ? qb : kb;
#pragma unroll
  for (int nt = 0; nt < 4; ++nt) {
    const int d = nt * 16 + col;                  // head dim 0..63
    const float bv = bias[j0 + wn * 64 + d];
    const int ifr = d >> 1;
    const float sgn = (d & 1) ? 1.0f : -1.0f;
#pragma unroll
    for (int mt = 0; mt < 4; ++mt) {
#pragma unroll
      for (int j = 0; j < 4; ++j) {
        int mg = m0 + wm * 64 + mt * 16 + rquad * 4 + j;
        int ms = mg & 1023, bi = mg >> 10;
        float v = acc[mt][nt][j] + bv;
        float p = __shfl_xor(v, 1, 64);           // partner dim (d^1), incl. its bias
        float s = ssin[ms * 32 + ifr], cv = scos[ms * 32 + ifr];
        float r = v * cv + sgn * p * s;           // even: v*c - p*s ; odd: v*c + p*s
        dst[(size_t)((bi * 12 + h) * 1024 + ms) * 64 + d] = f2bf(r);
      }
    }
  }
}

// ---------------- kernel 3: logits[b][h][m][n] = q.k, mask+tril+scale ----------------
// XCD-chunked: each XCD owns 12 bh-groups (q/k tiles stay L2-resident, ~3MB/XCD).
__global__ __launch_bounds__(256) void k_gemm2(
    const unsigned short* __restrict__ qb, const unsigned short* __restrict__ kbuf,
    const float* __restrict__ mask, float* __restrict__ out) {
  __shared__ __align__(16) unsigned short Qs[128 * 64];
  __shared__ __align__(16) unsigned short Ks[128 * 64];
  const int tid = threadIdx.x;
  const int wave = tid >> 6, lane = tid & 63;
  const int wm = wave >> 1, wn = wave & 1;
  // XCD swizzle: 6144 blocks, 768 per XCD = 12 bh x 64 tiles
  const int orig = blockIdx.x;
  const int xcd = orig & 7, idx = orig >> 3;      // idx in [0,768)
  const int bh = xcd * 12 + (idx >> 6);           // 0..95 = b*12+h
  const int tt = idx & 63;
  const int tm = tt >> 3, tn = tt & 7;
  const int b = bh / 12;
  const int lr = lane >> 3, kc = lane & 7;

  const unsigned short* qbase = qb   + (size_t)bh * (1024 * 64);
  const unsigned short* kbase = kbuf + (size_t)bh * (1024 * 64);

#pragma unroll
  for (int i = 0; i < 4; ++i) {
    int row = i * 32 + wave * 8 + lr;
    int gk = (kc ^ (row & 7)) << 3;
    gload_lds16(&qbase[(size_t)(tm * 128 + row) * 64 + gk], &Qs[(i * 32 + wave * 8) * 64]);
  }
#pragma unroll
  for (int i = 0; i < 4; ++i) {
    int row = i * 32 + wave * 8 + lr;
    int gk = (kc ^ (row & 7)) << 3;
    gload_lds16(&kbase[(size_t)(tn * 128 + row) * 64 + gk], &Ks[(i * 32 + wave * 8) * 64]);
  }
  asm volatile("s_waitcnt vmcnt(0)" ::: "memory");
  __syncthreads();

  f32x4 acc[4][4] = {};
#pragma unroll
  for (int kh = 0; kh < 2; ++kh) {
    short8 af[4], bfr[4];
#pragma unroll
    for (int mt = 0; mt < 4; ++mt) {
      int row = wm * 64 + mt * 16 + (lane & 15);
      int cs = (kh * 4 + (lane >> 4)) ^ (row & 7);
      af[mt] = *(const short8*)&Qs[row * 64 + cs * 8];
    }
#pragma unroll
    for (int nt = 0; nt < 4; ++nt) {
      int row = wn * 64 + nt * 16 + (lane & 15);
      int cs = (kh * 4 + (lane >> 4)) ^ (row & 7);
      bfr[nt] = *(const short8*)&Ks[row * 64 + cs * 8];
    }
#pragma unroll
    for (int mt = 0; mt < 4; ++mt)
#pragma unroll
      for (int nt = 0; nt < 4; ++nt)
        acc[mt][nt] = __builtin_amdgcn_mfma_f32_16x16x32_bf16(af[mt], bfr[nt], acc[mt][nt], 0, 0, 0);
  }

  float* obase = out + (size_t)bh * (1024 * 1024);
  const int col = lane & 15, rquad = lane >> 4;
  float m2v[4]; int ngv[4];
#pragma unroll
  for (int nt = 0; nt < 4; ++nt) {
    ngv[nt] = tn * 128 + wn * 64 + nt * 16 + col;
    m2v[nt] = mask[b * 1024 + ngv[nt]];
  }
#pragma unroll
  for (int mt = 0; mt < 4; ++mt) {
#pragma unroll
    for (int j = 0; j < 4; ++j) {
      int mg = tm * 128 + wm * 64 + mt * 16 + rquad * 4 + j;
      float m1 = mask[b * 1024 + mg];
      float* orow = obase + (size_t)mg * 1024;
#pragma unroll
      for (int nt = 0; nt < 4; ++nt) {
        float v = acc[mt][nt][j];
        v = v * m1 - NEGC * (1.0f - m1);
        v = v * m2v[nt] - NEGC * (1.0f - m2v[nt]);
        if (ngv[nt] < mg) v -= NEGC;           // tril(k=-1): n < m
        orow[ngv[nt]] = v * 0.125f;            // / sqrt(64)
      }
    }
  }
}

extern "C" void kernel_launch(void* const* d_in, const int* in_sizes, int n_in,
                              void* d_out, int out_size, void* d_ws, size_t ws_size,
                              hipStream_t stream) {
  const float* inputs = (const float*)d_in[0];  // [8][1024][768]
  const float* mask   = (const float*)d_in[1];  // [8][1024]
  const float* W      = (const float*)d_in[2];  // [768][1536]
  const float* bias   = (const float*)d_in[3];  // [1536]
  float* out = (float*)d_out;                   // [8][12][1024][1024]
  char* ws = (char*)d_ws;

  float* ssin = (float*)(ws);                                   // 128 KB
  float* scos = (float*)(ws + 131072);                          // 128 KB
  unsigned short* inA = (unsigned short*)(ws + 262144);         // 12.6 MB
  unsigned short* Wt  = (unsigned short*)(ws + 262144 + 12582912);            // 2.36 MB
  unsigned short* qb  = (unsigned short*)(ws + 262144 + 12582912 + 2359296);  // 12.6 MB
  unsigned short* kb  = (unsigned short*)(ws + 262144 + 12582912 + 2359296 + 12582912);

  hipLaunchKernelGGL(k_prep, dim3(6560), dim3(256), 0, stream,
                     inputs, inA, W, Wt, ssin, scos);
  hipLaunchKernelGGL(k_gemm1, dim3(768), dim3(256), 0, stream,
                     inA, Wt, bias, ssin, scos, qb, kb);
  hipLaunchKernelGGL(k_gemm2, dim3(6144), dim3(256), 0, stream, qb, kb, mask, out);
}